// Round 19
// baseline (575.518 us; speedup 1.0000x reference)
//
#include <hip/hip_runtime.h>

// ---------------------------------------------------------------------------
// ChatGLM attention block on MI355X (gfx950), bf16 MFMA pipeline.
//   S=2048, B=1, H=4096, NH=32, HD=128, ROT=64.
// Stages: cvt2(hs+Wqkv) -> GEMM1(qkv) -> cvt(Wd) -> rope(+V transpose)
//         -> attention -> GEMM2(split-K2) -> reduce+bias.
// GEMM: 256x256, BK=64, 8 waves, 4-phase/K-tile, ONE barrier per phase,
//   counted vmcnt(6) (r11 schedule, 226us / 40% MfmaUtil).
// Attention r19: KVBLK=64 (4 kv-subtiles/iter) — halves the serial
//   softmax-chain count vs r15's KVBLK=32 (the r8->r9 lever, reapplied).
//   512 blocks x 4 waves, wave owns 32 q-rows, V-prefetch, balanced pairing.
//   Live set ~190 VGPR < 256 at 2 waves/SIMD (no launch-bounds cap: r17
//   lesson).
// ---------------------------------------------------------------------------

#define S_LEN 2048
#define NHEAD 32
#define HDIM 128
#define HID 4096

typedef float f32x4 __attribute__((ext_vector_type(4)));
typedef __bf16 bf16x8 __attribute__((ext_vector_type(8)));
typedef __bf16 bf16x4 __attribute__((ext_vector_type(4)));
typedef _Float16 f16x4 __attribute__((ext_vector_type(4)));
typedef _Float16 f16x8 __attribute__((ext_vector_type(8)));

__device__ __forceinline__ void gload16(const void* g, void* l) {
  __builtin_amdgcn_global_load_lds(
      (const __attribute__((address_space(1))) void*)g,
      (__attribute__((address_space(3))) void*)l, 16, 0, 0);
}

__device__ __forceinline__ void cvt4(const float* in, __bf16* out, int i) {
  f32x4 v = *(const f32x4*)(in + (size_t)i * 4);
  bf16x4 o;
  o[0] = (__bf16)v[0]; o[1] = (__bf16)v[1];
  o[2] = (__bf16)v[2]; o[3] = (__bf16)v[3];
  *(bf16x4*)(out + (size_t)i * 4) = o;
}

// ------------------------- f32 -> bf16 converts ----------------------------
__global__ __launch_bounds__(256) void cvt_f32_bf16_kernel(
    const float* __restrict__ in, __bf16* __restrict__ out, int n4) {
  int i = blockIdx.x * 256 + threadIdx.x;
  if (i >= n4) return;
  cvt4(in, out, i);
}

__global__ __launch_bounds__(256) void cvt2_kernel(
    const float* __restrict__ in1, __bf16* __restrict__ out1, int n4_1,
    const float* __restrict__ in2, __bf16* __restrict__ out2, int n4_2) {
  int i = blockIdx.x * 256 + threadIdx.x;
  if (i < n4_1) {
    cvt4(in1, out1, i);
  } else if (i - n4_1 < n4_2) {
    cvt4(in2, out2, i - n4_1);
  }
}

// ------------------- shared GEMM staging / fragment utils ------------------
__device__ __forceinline__ void stage_half(const __bf16* __restrict__ G,
                                           int grow0, int Kstride, int kofs,
                                           __bf16* lds_half, int tid) {
#pragma unroll
  for (int i = 0; i < 2; ++i) {
    int idx = i * 512 + tid;
    int rr = idx >> 3;
    int offp = (idx & 7) * 16;
    int off = offp ^ ((rr & 7) << 4);
    const char* src =
        (const char*)(G + (size_t)(grow0 + rr) * Kstride + kofs) + off;
    char* dst = (char*)lds_half + idx * 16;
    gload16(src, dst);
  }
}

__device__ __forceinline__ bf16x8 ldsfrag(const __bf16* hb, int rowin, int ks,
                                          int lg) {
  int off = ((ks * 64 + lg * 16) ^ ((rowin & 7) << 4));
  return *(const bf16x8*)((const char*)hb + rowin * 128 + off);
}

#define READ_A(DST, SLOT)                                                     \
  _Pragma("unroll") for (int mi = 0; mi < 4; ++mi)                            \
      _Pragma("unroll") for (int ks = 0; ks < 2; ++ks) DST[mi][ks] =          \
      ldsfrag(SLOT, wm * 64 + mi * 16 + lr, ks, lg);

#define READ_B(DST, SLOT)                                                     \
  _Pragma("unroll") for (int nj = 0; nj < 2; ++nj)                            \
      _Pragma("unroll") for (int ks = 0; ks < 2; ++ks) DST[nj][ks] =          \
      ldsfrag(SLOT, wn * 32 + nj * 16 + lr, ks, lg);

#define MFMA_Q(MH, NH, AFR, BFR)                                              \
  __builtin_amdgcn_s_setprio(1);                                              \
  _Pragma("unroll") for (int mi = 0; mi < 4; ++mi)                            \
      _Pragma("unroll") for (int nj = 0; nj < 2; ++nj)                        \
          _Pragma("unroll") for (int ks = 0; ks < 2; ++ks)                    \
              acc[MH][NH][mi][nj] =                                           \
      __builtin_amdgcn_mfma_f32_16x16x32_bf16(AFR[mi][ks], BFR[nj][ks],       \
                                              acc[MH][NH][mi][nj], 0, 0, 0);  \
  __builtin_amdgcn_s_setprio(0);

#define BAR asm volatile("s_barrier" ::: "memory");

// --------------------- 256^2 GEMM: C = A*B^T (+ bias) ----------------------
// OUT_MODE: 1 = bf16 + bias, 2 = f32 partial (split-K, offset kh*M*N).
template <int OUT_MODE>
__global__ __launch_bounds__(512, 2) void gemm256_kernel(
    const __bf16* __restrict__ A, const __bf16* __restrict__ B,
    const float* __restrict__ bias, void* __restrict__ Cout, int M, int N,
    int Kstride, int klen, int mtiles, int ksplit) {
  __shared__ __align__(16) __bf16 As[2][2][128 * 64];
  __shared__ __align__(16) __bf16 Bs[2][2][128 * 64];
  const int tid = threadIdx.x;
  int bid = blockIdx.x;
  int kh = 0;
  if (ksplit == 2) { kh = bid & 1; bid >>= 1; }
  const int kbase = kh * klen;
  int per_patch = mtiles * 8;
  int p = bid / per_patch, r = bid % per_patch;
  int mt = r % mtiles, nt = p * 8 + r / mtiles;
  int m0 = mt * 256, n0 = nt * 256;
  const int wid = tid >> 6, l = tid & 63;
  const int wm = wid >> 2, wn = wid & 3;  // 2 x 4 waves, wave = 64 x 32
  const int lr = l & 15, lg = l >> 4;
  const int nk = klen >> 6;

  f32x4 acc[2][2][4][2];
#pragma unroll
  for (int a = 0; a < 2; ++a)
#pragma unroll
    for (int b = 0; b < 2; ++b)
#pragma unroll
      for (int c = 0; c < 4; ++c)
#pragma unroll
        for (int d = 0; d < 2; ++d) acc[a][b][c][d] = 0.f;

  stage_half(A, m0, Kstride, kbase, &As[0][0][0], tid);
  stage_half(B, n0, Kstride, kbase, &Bs[0][0][0], tid);
  stage_half(B, n0 + 128, Kstride, kbase, &Bs[0][1][0], tid);
  stage_half(A, m0 + 128, Kstride, kbase, &As[0][1][0], tid);
  if (nk > 1) {
    stage_half(A, m0, Kstride, kbase + 64, &As[1][0][0], tid);
    stage_half(B, n0, Kstride, kbase + 64, &Bs[1][0][0], tid);
    stage_half(B, n0 + 128, Kstride, kbase + 64, &Bs[1][1][0], tid);
    asm volatile("s_waitcnt vmcnt(6)" ::: "memory");
  } else {
    asm volatile("s_waitcnt vmcnt(0)" ::: "memory");
  }
  BAR;

  for (int t = 0; t < nk; ++t) {
    const int cur = t & 1, nxt = cur ^ 1;
    const int kt1 = kbase + (t + 1) * 64;
    const int kt2 = kbase + (t + 2) * 64;
    const bool s1 = (t + 1 < nk), s2 = (t + 2 < nk);
    bf16x8 a[4][2], b0[2][2], b1[2][2];

    // ---- p1 ----
    READ_A(a, &As[cur][0][0]);
    READ_B(b0, &Bs[cur][0][0]);
    if (s1) stage_half(A, m0 + 128, Kstride, kt1, &As[nxt][1][0], tid);
    BAR;
    MFMA_Q(0, 0, a, b0);

    // ---- p2 ----
    READ_B(b1, &Bs[cur][1][0]);
    if (s2) stage_half(A, m0, Kstride, kt2, &As[cur][0][0], tid);
    BAR;
    MFMA_Q(0, 1, a, b1);

    // ---- p3 ----
    READ_A(a, &As[cur][1][0]);
    if (s2) stage_half(B, n0 + 128, Kstride, kt2, &Bs[cur][1][0], tid);
    BAR;
    MFMA_Q(1, 1, a, b1);

    // ---- p4 ----
    if (s2) stage_half(B, n0, Kstride, kt2, &Bs[cur][0][0], tid);
    BAR;
    MFMA_Q(1, 0, a, b0);
    if (s2)
      asm volatile("s_waitcnt vmcnt(6)" ::: "memory");
    else
      asm volatile("s_waitcnt vmcnt(0)" ::: "memory");
  }

  float* outF = (float*)Cout;
  if (OUT_MODE == 2) outF += (size_t)kh * M * N;
#pragma unroll
  for (int mh = 0; mh < 2; ++mh)
#pragma unroll
    for (int nh = 0; nh < 2; ++nh)
#pragma unroll
      for (int mi = 0; mi < 4; ++mi)
#pragma unroll
        for (int nj = 0; nj < 2; ++nj) {
          int row = m0 + mh * 128 + wm * 64 + mi * 16 + lg * 4;
          int col = n0 + nh * 128 + wn * 32 + nj * 16 + lr;
          float bv = (OUT_MODE == 2) ? 0.f : bias[col];
          f32x4 v = acc[mh][nh][mi][nj];
#pragma unroll
          for (int j = 0; j < 4; ++j) {
            float o = v[j] + bv;
            if (OUT_MODE == 1)
              ((__bf16*)Cout)[(size_t)(row + j) * N + col] = (__bf16)o;
            else
              outF[(size_t)(row + j) * N + col] = o;
          }
        }
}

// ---------------- split-K reduce: out = p0 + p1 + bias ---------------------
__global__ __launch_bounds__(256) void reduce_addbias_kernel(
    const float* __restrict__ p0, const float* __restrict__ p1,
    const float* __restrict__ bias, float* __restrict__ out) {
  int i = blockIdx.x * 256 + threadIdx.x;
  int col = (i * 4) & (HID - 1);
  f32x4 a = *(const f32x4*)(p0 + (size_t)i * 4);
  f32x4 b = *(const f32x4*)(p1 + (size_t)i * 4);
  f32x4 c = *(const f32x4*)(bias + col);
  a = a + b + c;
  *(f32x4*)(out + (size_t)i * 4) = a;
}

// ------------------------------- RoPE -------------------------------------
__global__ __launch_bounds__(256) void rope_kernel(
    const __bf16* __restrict__ qkv, const int* __restrict__ pos_ids,
    __bf16* __restrict__ Q, __bf16* __restrict__ K, _Float16* __restrict__ VT) {
  int h = blockIdx.x & 31, sb = blockIdx.x >> 5;
  int s0 = sb * 64;
  int t = threadIdx.x;
  __shared__ float cs[64][2][2][32];
  __shared__ _Float16 vs[64][132];

  for (int idx = t; idx < 64 * 64; idx += 256) {
    int sl = idx >> 6, half = (idx >> 5) & 1, i = idx & 31;
    int p = pos_ids[half * S_LEN + s0 + sl];
    float f = powf(10000.f, -(float)i / 32.f);
    float ang = (float)p * f;
    cs[sl][half][0][i] = cosf(ang);
    cs[sl][half][1][i] = sinf(ang);
  }
#pragma unroll
  for (int c = 0; c < 4; c++) {
    int chunk = c * 256 + t;
    int slv = chunk >> 4, co = (chunk & 15) * 8;
    const __bf16* vsrc =
        qkv + (size_t)(s0 + slv) * (NHEAD * 3 * HDIM) + h * 384 + 256 + co;
    bf16x8 vv = *(const bf16x8*)vsrc;
    f16x4 a, b;
#pragma unroll
    for (int j = 0; j < 4; j++) {
      a[j] = (_Float16)(float)vv[j];
      b[j] = (_Float16)(float)vv[4 + j];
    }
    *(f16x4*)&vs[slv][co] = a;
    *(f16x4*)&vs[slv][co + 4] = b;
  }
  __syncthreads();

  {
    int sl = t >> 2, role = t & 3;
    int isK = role >> 1, half = role & 1;
    const __bf16* src = qkv + (size_t)(s0 + sl) * (NHEAD * 3 * HDIM) + h * 384 +
                        isK * 128 + half * 64;
    float scale = isK ? 1.f : 0.08838834764831845f;  // 1/sqrt(128)
    float x[64];
    bf16x8 buf[8];
#pragma unroll
    for (int c = 0; c < 8; c++) buf[c] = *(const bf16x8*)(src + c * 8);
#pragma unroll
    for (int c = 0; c < 8; c++)
#pragma unroll
      for (int j = 0; j < 8; j++) x[c * 8 + j] = (float)buf[c][j];
    bf16x8 ob[8];
#pragma unroll
    for (int i = 0; i < 64; i++) {
      int ii = i & 31;
      float cv = cs[sl][half][0][ii], sv = cs[sl][half][1][ii];
      float partner = (i < 32) ? x[i + 32] : x[i - 32];
      float sgn = (i < 32) ? -1.f : 1.f;
      float o = (x[i] * cv + sgn * partner * sv) * scale;
      ob[i >> 3][i & 7] = (__bf16)o;
    }
    __bf16* dst = (isK ? K : Q) + ((size_t)h * S_LEN + s0 + sl) * HDIM + half * 64;
#pragma unroll
    for (int c = 0; c < 8; c++) *(bf16x8*)(dst + c * 8) = ob[c];
  }

#pragma unroll
  for (int c = 0; c < 4; c++) {
    int chunk = c * 256 + t;
    int d = chunk >> 3, so = (chunk & 7) * 8;
    f16x8 o;
#pragma unroll
    for (int j = 0; j < 8; j++) o[j] = vs[so + j][d];
    *(f16x8*)(VT + ((size_t)h * HDIM + d) * S_LEN + s0 + so) = o;
  }
}

// ---------------------------- Flash attention ------------------------------
// grid = 512; balanced pairing: qb(b) + qb(b+256) == 15 (equal per-CU work).
// 4 waves/block, wave owns 32 q rows (frags A,B). KVBLK=64: 4 kv-subtiles
// per iteration — halves the serial softmax-chain count vs KVBLK=32.
__global__ __launch_bounds__(256, 2) void attn_kernel(
    const __bf16* __restrict__ Q, const __bf16* __restrict__ K,
    const _Float16* __restrict__ VT, __bf16* __restrict__ ctx) {
  int b = blockIdx.x;
  int h = b & 31;
  int x = b >> 5;
  int qb = (b < 256) ? (15 - x) : (x - 8);
  int w = threadIdx.x >> 6, l = threadIdx.x & 63;
  int lr = l & 15, lg = l >> 4;
  int q0 = qb * 128 + w * 32;
  const __bf16* Qh = Q + (size_t)h * S_LEN * HDIM;
  const __bf16* Kh = K + (size_t)h * S_LEN * HDIM;
  const _Float16* Vh = VT + (size_t)h * HDIM * S_LEN;

  bf16x8 qfA[4], qfB[4];
#pragma unroll
  for (int kk = 0; kk < 4; kk++) {
    qfA[kk] = *(const bf16x8*)(Qh + (size_t)(q0 + lr) * HDIM + kk * 32 + lg * 8);
    qfB[kk] =
        *(const bf16x8*)(Qh + (size_t)(q0 + 16 + lr) * HDIM + kk * 32 + lg * 8);
  }

  f32x4 accA[8], accB[8];
#pragma unroll
  for (int tt = 0; tt < 8; tt++) { accA[tt] = 0.f; accB[tt] = 0.f; }
  float mA = -INFINITY, lsA = 0.f, mB = -INFINITY, lsB = 0.f;
  int qgA = q0 + lr, qgB = q0 + 16 + lr;
  int qmax = q0 + 31;

  for (int kv0 = 0; kv0 <= qmax; kv0 += 64) {
    // ---- QK^T over 4 kv-subtiles ----
    f32x4 stA[4], stB[4];
#pragma unroll
    for (int s = 0; s < 4; s++) { stA[s] = 0.f; stB[s] = 0.f; }
#pragma unroll
    for (int kk = 0; kk < 4; kk++) {
#pragma unroll
      for (int s = 0; s < 4; s++) {
        bf16x8 kf = *(const bf16x8*)(Kh + (size_t)(kv0 + s * 16 + lr) * HDIM +
                                     kk * 32 + lg * 8);
        stA[s] =
            __builtin_amdgcn_mfma_f32_16x16x32_bf16(kf, qfA[kk], stA[s], 0, 0, 0);
        stB[s] =
            __builtin_amdgcn_mfma_f32_16x16x32_bf16(kf, qfB[kk], stB[s], 0, 0, 0);
      }
    }

    // ---- V prefetch, subtiles 0..1 (hides under softmax) ----
    f16x4 vb0[8], vb1[8];
#pragma unroll
    for (int tt = 0; tt < 8; tt++) {
      const _Float16* vcol = Vh + (size_t)(tt * 16 + lr) * S_LEN;
      vb0[tt] = *(const f16x4*)(vcol + kv0 + lg * 4);
      vb1[tt] = *(const f16x4*)(vcol + kv0 + 16 + lg * 4);
    }

    // ---- causal mask + per-row max over 4 subtiles ----
    float tmA = -INFINITY, tmB = -INFINITY;
#pragma unroll
    for (int s = 0; s < 4; s++) {
#pragma unroll
      for (int j = 0; j < 4; j++) {
        int kvg = kv0 + s * 16 + lg * 4 + j;
        if (kvg > qgA) stA[s][j] = -INFINITY;
        if (kvg > qgB) stB[s][j] = -INFINITY;
        tmA = fmaxf(tmA, stA[s][j]);
        tmB = fmaxf(tmB, stB[s][j]);
      }
    }
    tmA = fmaxf(tmA, __shfl_xor(tmA, 16));
    tmA = fmaxf(tmA, __shfl_xor(tmA, 32));
    tmB = fmaxf(tmB, __shfl_xor(tmB, 16));
    tmB = fmaxf(tmB, __shfl_xor(tmB, 32));
    int need = __any((tmA > mA) || (tmB > mB));
    float mnA = fmaxf(mA, tmA), mnB = fmaxf(mB, tmB);

    f16x4 paA[4], paB[4];
    float tsA = 0.f, tsB = 0.f;
#pragma unroll
    for (int s = 0; s < 4; s++) {
#pragma unroll
      for (int j = 0; j < 4; j++) {
        float pA = __expf(stA[s][j] - mnA);
        float pB = __expf(stB[s][j] - mnB);
        tsA += pA;
        tsB += pB;
        paA[s][j] = (_Float16)pA;
        paB[s][j] = (_Float16)pB;
      }
    }
    tsA += __shfl_xor(tsA, 16);
    tsA += __shfl_xor(tsA, 32);
    tsB += __shfl_xor(tsB, 16);
    tsB += __shfl_xor(tsB, 32);

    // ---- V prefetch, subtiles 2..3 (hides under rescale + PV of 0..1) ----
    f16x4 vb2[8], vb3[8];
#pragma unroll
    for (int tt = 0; tt < 8; tt++) {
      const _Float16* vcol = Vh + (size_t)(tt * 16 + lr) * S_LEN;
      vb2[tt] = *(const f16x4*)(vcol + kv0 + 32 + lg * 4);
      vb3[tt] = *(const f16x4*)(vcol + kv0 + 48 + lg * 4);
    }

    if (need) {
      float scA = __expf(mA - mnA), scB = __expf(mB - mnB);
      lsA = lsA * scA + tsA;
      lsB = lsB * scB + tsB;
      float sAj[4], sBj[4];
#pragma unroll
      for (int j = 0; j < 4; j++) {
        sAj[j] = __shfl(scA, lg * 4 + j);
        sBj[j] = __shfl(scB, lg * 4 + j);
      }
#pragma unroll
      for (int tt = 0; tt < 8; tt++)
#pragma unroll
        for (int j = 0; j < 4; j++) {
          accA[tt][j] *= sAj[j];
          accB[tt][j] *= sBj[j];
        }
    } else {
      lsA += tsA;
      lsB += tsB;
    }
    mA = mnA; mB = mnB;

    // ---- PV: 4 subtiles ----
#pragma unroll
    for (int tt = 0; tt < 8; tt++) {
      accA[tt] =
          __builtin_amdgcn_mfma_f32_16x16x16f16(paA[0], vb0[tt], accA[tt], 0, 0, 0);
      accB[tt] =
          __builtin_amdgcn_mfma_f32_16x16x16f16(paB[0], vb0[tt], accB[tt], 0, 0, 0);
      accA[tt] =
          __builtin_amdgcn_mfma_f32_16x16x16f16(paA[1], vb1[tt], accA[tt], 0, 0, 0);
      accB[tt] =
          __builtin_amdgcn_mfma_f32_16x16x16f16(paB[1], vb1[tt], accB[tt], 0, 0, 0);
      accA[tt] =
          __builtin_amdgcn_mfma_f32_16x16x16f16(paA[2], vb2[tt], accA[tt], 0, 0, 0);
      accB[tt] =
          __builtin_amdgcn_mfma_f32_16x16x16f16(paB[2], vb2[tt], accB[tt], 0, 0, 0);
      accA[tt] =
          __builtin_amdgcn_mfma_f32_16x16x16f16(paA[3], vb3[tt], accA[tt], 0, 0, 0);
      accB[tt] =
          __builtin_amdgcn_mfma_f32_16x16x16f16(paB[3], vb3[tt], accB[tt], 0, 0, 0);
    }
  }

  float rA[4], rB[4];
#pragma unroll
  for (int j = 0; j < 4; j++) {
    rA[j] = 1.f / __shfl(lsA, lg * 4 + j);
    rB[j] = 1.f / __shfl(lsB, lg * 4 + j);
  }
#pragma unroll
  for (int tt = 0; tt < 8; tt++) {
#pragma unroll
    for (int j = 0; j < 4; j++) {
      int qoA = q0 + lg * 4 + j;
      int qoB = q0 + 16 + lg * 4 + j;
      ctx[(size_t)qoA * (NHEAD * HDIM) + h * HDIM + tt * 16 + lr] =
          (__bf16)(accA[tt][j] * rA[j]);
      ctx[(size_t)qoB * (NHEAD * HDIM) + h * HDIM + tt * 16 + lr] =
          (__bf16)(accB[tt][j] * rB[j]);
    }
  }
}

// ---------------------------------------------------------------------------
extern "C" void kernel_launch(void* const* d_in, const int* in_sizes, int n_in,
                              void* d_out, int out_size, void* d_ws,
                              size_t ws_size, hipStream_t stream) {
  const float* hs = (const float*)d_in[0];
  const int* pos_ids = (const int*)d_in[1];
  const float* Wqkv = (const float*)d_in[4];
  const float* bqkv = (const float*)d_in[5];
  const float* Wd = (const float*)d_in[6];
  const float* bd = (const float*)d_in[7];
  float* out = (float*)d_out;

  char* ws = (char*)d_ws;
  constexpr size_t OFF_W = 16777216ULL;
  constexpr size_t OFF_QKV = OFF_W + 100663296ULL;
  constexpr size_t OFF_Q = OFF_QKV + 50331648ULL;
  constexpr size_t OFF_K = OFF_Q + 16777216ULL;
  constexpr size_t OFF_V = OFF_K + 16777216ULL;
  __bf16* hsb = (__bf16*)(ws);
  __bf16* wqkvb = (__bf16*)(ws + OFF_W);
  __bf16* wdb = (__bf16*)(ws + OFF_W);  // aliases wqkvb (dead after GEMM1)
  float* pk = (float*)(ws + OFF_W + 33554432ULL);  // 2 x 32MB split-K partials
  __bf16* qkvb = (__bf16*)(ws + OFF_QKV);
  __bf16* ctxb = qkvb;                  // aliases qkv (dead after rope)
  __bf16* Qb = (__bf16*)(ws + OFF_Q);
  __bf16* Kb = (__bf16*)(ws + OFF_K);
  _Float16* Vtb = (_Float16*)(ws + OFF_V);

  const int n4_hs = S_LEN * HID / 4;
  const int n4_w = 3 * HID * HID / 4;
  cvt2_kernel<<<(n4_hs + n4_w + 255) / 256, 256, 0, stream>>>(
      hs, hsb, n4_hs, Wqkv, wqkvb, n4_w);

  // GEMM1: [2048,4096] x [12288,4096]^T -> bf16 qkv. 8x48 tiles of 256^2.
  gemm256_kernel<1><<<8 * 48, 512, 0, stream>>>(hsb, wqkvb, bqkv, qkvb, S_LEN,
                                                3 * HID, HID, HID, 8, 1);

  cvt_f32_bf16_kernel<<<(HID * HID) / 4 / 256, 256, 0, stream>>>(
      Wd, wdb, HID * HID / 4);

  rope_kernel<<<NHEAD * (S_LEN / 64), 256, 0, stream>>>(qkvb, pos_ids, Qb, Kb,
                                                        Vtb);

  attn_kernel<<<NHEAD * (S_LEN / 128), 256, 0, stream>>>(Qb, Kb, Vtb, ctxb);

  // GEMM2 split-K=2: 256 blocks (1/CU), f32 partials, then reduce + bias.
  gemm256_kernel<2><<<2 * 8 * 16, 512, 0, stream>>>(ctxb, wdb, bd, pk, S_LEN,
                                                    HID, HID, HID / 2, 8, 2);
  reduce_addbias_kernel<<<(S_LEN * HID) / 4 / 256, 256, 0, stream>>>(
      pk, pk + (size_t)S_LEN * HID, bd, out);
}

// Round 20
// 561.199 us; speedup vs baseline: 1.0255x; 1.0255x over previous
//
#include <hip/hip_runtime.h>

// ---------------------------------------------------------------------------
// ChatGLM attention block on MI355X (gfx950), bf16 MFMA pipeline.
//   S=2048, B=1, H=4096, NH=32, HD=128, ROT=64.
// FINAL consolidated configuration (r18, measured 561.8 us):
//   cvt2(hs+Wqkv) -> GEMM1(qkv) -> cvt(Wd) -> rope(+V transpose)
//   -> attention -> GEMM2(split-K2) -> reduce+bias.
// GEMM: 256x256, BK=64, 8 waves, 4-phase/K-tile, ONE barrier per phase
// (next phase's ds_reads issue right after the MFMA cluster so the LDS
// drain runs under the matrix pipe), counted vmcnt(6) once per K-tile.
// Attention: 512 blocks x 4 waves, wave owns 32 q-rows, KVBLK=32,
// V-prefetch before softmax, balanced CU pairing (qb pairs sum to 15).
// Search history: GEMM schedule (r3-r11) and geometry (r12/r13) confirm
// this GEMM as the structure's optimum; attn restructurings (r16 tile-
// shrink, r17 launch-bounds, r19 KVBLK=64) all regressed.
// ---------------------------------------------------------------------------

#define S_LEN 2048
#define NHEAD 32
#define HDIM 128
#define HID 4096

typedef float f32x4 __attribute__((ext_vector_type(4)));
typedef __bf16 bf16x8 __attribute__((ext_vector_type(8)));
typedef __bf16 bf16x4 __attribute__((ext_vector_type(4)));
typedef _Float16 f16x4 __attribute__((ext_vector_type(4)));
typedef _Float16 f16x8 __attribute__((ext_vector_type(8)));

__device__ __forceinline__ void gload16(const void* g, void* l) {
  __builtin_amdgcn_global_load_lds(
      (const __attribute__((address_space(1))) void*)g,
      (__attribute__((address_space(3))) void*)l, 16, 0, 0);
}

__device__ __forceinline__ void cvt4(const float* in, __bf16* out, int i) {
  f32x4 v = *(const f32x4*)(in + (size_t)i * 4);
  bf16x4 o;
  o[0] = (__bf16)v[0]; o[1] = (__bf16)v[1];
  o[2] = (__bf16)v[2]; o[3] = (__bf16)v[3];
  *(bf16x4*)(out + (size_t)i * 4) = o;
}

// ------------------------- f32 -> bf16 converts ----------------------------
__global__ __launch_bounds__(256) void cvt_f32_bf16_kernel(
    const float* __restrict__ in, __bf16* __restrict__ out, int n4) {
  int i = blockIdx.x * 256 + threadIdx.x;
  if (i >= n4) return;
  cvt4(in, out, i);
}

__global__ __launch_bounds__(256) void cvt2_kernel(
    const float* __restrict__ in1, __bf16* __restrict__ out1, int n4_1,
    const float* __restrict__ in2, __bf16* __restrict__ out2, int n4_2) {
  int i = blockIdx.x * 256 + threadIdx.x;
  if (i < n4_1) {
    cvt4(in1, out1, i);
  } else if (i - n4_1 < n4_2) {
    cvt4(in2, out2, i - n4_1);
  }
}

// ------------------- shared GEMM staging / fragment utils ------------------
__device__ __forceinline__ void stage_half(const __bf16* __restrict__ G,
                                           int grow0, int Kstride, int kofs,
                                           __bf16* lds_half, int tid) {
#pragma unroll
  for (int i = 0; i < 2; ++i) {
    int idx = i * 512 + tid;
    int rr = idx >> 3;
    int offp = (idx & 7) * 16;
    int off = offp ^ ((rr & 7) << 4);
    const char* src =
        (const char*)(G + (size_t)(grow0 + rr) * Kstride + kofs) + off;
    char* dst = (char*)lds_half + idx * 16;
    gload16(src, dst);
  }
}

__device__ __forceinline__ bf16x8 ldsfrag(const __bf16* hb, int rowin, int ks,
                                          int lg) {
  int off = ((ks * 64 + lg * 16) ^ ((rowin & 7) << 4));
  return *(const bf16x8*)((const char*)hb + rowin * 128 + off);
}

#define READ_A(DST, SLOT)                                                     \
  _Pragma("unroll") for (int mi = 0; mi < 4; ++mi)                            \
      _Pragma("unroll") for (int ks = 0; ks < 2; ++ks) DST[mi][ks] =          \
      ldsfrag(SLOT, wm * 64 + mi * 16 + lr, ks, lg);

#define READ_B(DST, SLOT)                                                     \
  _Pragma("unroll") for (int nj = 0; nj < 2; ++nj)                            \
      _Pragma("unroll") for (int ks = 0; ks < 2; ++ks) DST[nj][ks] =          \
      ldsfrag(SLOT, wn * 32 + nj * 16 + lr, ks, lg);

#define MFMA_Q(MH, NH, AFR, BFR)                                              \
  __builtin_amdgcn_s_setprio(1);                                              \
  _Pragma("unroll") for (int mi = 0; mi < 4; ++mi)                            \
      _Pragma("unroll") for (int nj = 0; nj < 2; ++nj)                        \
          _Pragma("unroll") for (int ks = 0; ks < 2; ++ks)                    \
              acc[MH][NH][mi][nj] =                                           \
      __builtin_amdgcn_mfma_f32_16x16x32_bf16(AFR[mi][ks], BFR[nj][ks],       \
                                              acc[MH][NH][mi][nj], 0, 0, 0);  \
  __builtin_amdgcn_s_setprio(0);

#define BAR asm volatile("s_barrier" ::: "memory");

// --------------------- 256^2 GEMM: C = A*B^T (+ bias) ----------------------
// OUT_MODE: 1 = bf16 + bias, 2 = f32 partial (split-K, offset kh*M*N).
template <int OUT_MODE>
__global__ __launch_bounds__(512, 2) void gemm256_kernel(
    const __bf16* __restrict__ A, const __bf16* __restrict__ B,
    const float* __restrict__ bias, void* __restrict__ Cout, int M, int N,
    int Kstride, int klen, int mtiles, int ksplit) {
  __shared__ __align__(16) __bf16 As[2][2][128 * 64];
  __shared__ __align__(16) __bf16 Bs[2][2][128 * 64];
  const int tid = threadIdx.x;
  int bid = blockIdx.x;
  int kh = 0;
  if (ksplit == 2) { kh = bid & 1; bid >>= 1; }
  const int kbase = kh * klen;
  int per_patch = mtiles * 8;
  int p = bid / per_patch, r = bid % per_patch;
  int mt = r % mtiles, nt = p * 8 + r / mtiles;
  int m0 = mt * 256, n0 = nt * 256;
  const int wid = tid >> 6, l = tid & 63;
  const int wm = wid >> 2, wn = wid & 3;  // 2 x 4 waves, wave = 64 x 32
  const int lr = l & 15, lg = l >> 4;
  const int nk = klen >> 6;

  f32x4 acc[2][2][4][2];
#pragma unroll
  for (int a = 0; a < 2; ++a)
#pragma unroll
    for (int b = 0; b < 2; ++b)
#pragma unroll
      for (int c = 0; c < 4; ++c)
#pragma unroll
        for (int d = 0; d < 2; ++d) acc[a][b][c][d] = 0.f;

  // Prologue: tile0 all 4 half-tiles + tile1's {A0,B0,B1} (A1(1) comes at
  // t0-p1). vmcnt(6): tile0 landed, 3 half-tiles in flight.
  stage_half(A, m0, Kstride, kbase, &As[0][0][0], tid);
  stage_half(B, n0, Kstride, kbase, &Bs[0][0][0], tid);
  stage_half(B, n0 + 128, Kstride, kbase, &Bs[0][1][0], tid);
  stage_half(A, m0 + 128, Kstride, kbase, &As[0][1][0], tid);
  if (nk > 1) {
    stage_half(A, m0, Kstride, kbase + 64, &As[1][0][0], tid);
    stage_half(B, n0, Kstride, kbase + 64, &Bs[1][0][0], tid);
    stage_half(B, n0 + 128, Kstride, kbase + 64, &Bs[1][1][0], tid);
    asm volatile("s_waitcnt vmcnt(6)" ::: "memory");
  } else {
    asm volatile("s_waitcnt vmcnt(0)" ::: "memory");
  }
  BAR;

  // ONE barrier per phase; next phase's reads issue right after the MFMA
  // cluster issues, so their LDS drain executes under the MFMA pipeline.
  for (int t = 0; t < nk; ++t) {
    const int cur = t & 1, nxt = cur ^ 1;
    const int kt1 = kbase + (t + 1) * 64;
    const int kt2 = kbase + (t + 2) * 64;
    const bool s1 = (t + 1 < nk), s2 = (t + 2 < nk);
    bf16x8 a[4][2], b0[2][2], b1[2][2];

    // ---- p1 ----
    READ_A(a, &As[cur][0][0]);
    READ_B(b0, &Bs[cur][0][0]);
    if (s1) stage_half(A, m0 + 128, Kstride, kt1, &As[nxt][1][0], tid);
    BAR;
    MFMA_Q(0, 0, a, b0);

    // ---- p2 ----
    READ_B(b1, &Bs[cur][1][0]);
    if (s2) stage_half(A, m0, Kstride, kt2, &As[cur][0][0], tid);
    BAR;
    MFMA_Q(0, 1, a, b1);

    // ---- p3 ----
    READ_A(a, &As[cur][1][0]);
    if (s2) stage_half(B, n0 + 128, Kstride, kt2, &Bs[cur][1][0], tid);
    BAR;
    MFMA_Q(1, 1, a, b1);

    // ---- p4 ----
    if (s2) stage_half(B, n0, Kstride, kt2, &Bs[cur][0][0], tid);
    BAR;
    MFMA_Q(1, 0, a, b0);
    if (s2)
      asm volatile("s_waitcnt vmcnt(6)" ::: "memory");  // t+1 fully landed
    else
      asm volatile("s_waitcnt vmcnt(0)" ::: "memory");
  }

  // Epilogue: C/D layout col=lane&15, row=(lane>>4)*4+j.
  float* outF = (float*)Cout;
  if (OUT_MODE == 2) outF += (size_t)kh * M * N;
#pragma unroll
  for (int mh = 0; mh < 2; ++mh)
#pragma unroll
    for (int nh = 0; nh < 2; ++nh)
#pragma unroll
      for (int mi = 0; mi < 4; ++mi)
#pragma unroll
        for (int nj = 0; nj < 2; ++nj) {
          int row = m0 + mh * 128 + wm * 64 + mi * 16 + lg * 4;
          int col = n0 + nh * 128 + wn * 32 + nj * 16 + lr;
          float bv = (OUT_MODE == 2) ? 0.f : bias[col];
          f32x4 v = acc[mh][nh][mi][nj];
#pragma unroll
          for (int j = 0; j < 4; ++j) {
            float o = v[j] + bv;
            if (OUT_MODE == 1)
              ((__bf16*)Cout)[(size_t)(row + j) * N + col] = (__bf16)o;
            else
              outF[(size_t)(row + j) * N + col] = o;
          }
        }
}

// ---------------- split-K reduce: out = p0 + p1 + bias ---------------------
__global__ __launch_bounds__(256) void reduce_addbias_kernel(
    const float* __restrict__ p0, const float* __restrict__ p1,
    const float* __restrict__ bias, float* __restrict__ out) {
  int i = blockIdx.x * 256 + threadIdx.x;  // i indexes f32x4 chunks
  int col = (i * 4) & (HID - 1);
  f32x4 a = *(const f32x4*)(p0 + (size_t)i * 4);
  f32x4 b = *(const f32x4*)(p1 + (size_t)i * 4);
  f32x4 c = *(const f32x4*)(bias + col);
  a = a + b + c;
  *(f32x4*)(out + (size_t)i * 4) = a;
}

// ------------------------------- RoPE -------------------------------------
// Block = (head h, 64-s chunk). Reads qkv [S][NH*384] bf16.
// Writes Q,K [NH][S][HD] bf16 (Q scaled by 1/sqrt(HD)), VT [NH][HD][S] f16.
__global__ __launch_bounds__(256) void rope_kernel(
    const __bf16* __restrict__ qkv, const int* __restrict__ pos_ids,
    __bf16* __restrict__ Q, __bf16* __restrict__ K, _Float16* __restrict__ VT) {
  int h = blockIdx.x & 31, sb = blockIdx.x >> 5;
  int s0 = sb * 64;
  int t = threadIdx.x;
  __shared__ float cs[64][2][2][32];
  __shared__ _Float16 vs[64][132];

  for (int idx = t; idx < 64 * 64; idx += 256) {
    int sl = idx >> 6, half = (idx >> 5) & 1, i = idx & 31;
    int p = pos_ids[half * S_LEN + s0 + sl];
    float f = powf(10000.f, -(float)i / 32.f);
    float ang = (float)p * f;
    cs[sl][half][0][i] = cosf(ang);
    cs[sl][half][1][i] = sinf(ang);
  }
#pragma unroll
  for (int c = 0; c < 4; c++) {
    int chunk = c * 256 + t;
    int slv = chunk >> 4, co = (chunk & 15) * 8;
    const __bf16* vsrc =
        qkv + (size_t)(s0 + slv) * (NHEAD * 3 * HDIM) + h * 384 + 256 + co;
    bf16x8 vv = *(const bf16x8*)vsrc;
    f16x4 a, b;
#pragma unroll
    for (int j = 0; j < 4; j++) {
      a[j] = (_Float16)(float)vv[j];
      b[j] = (_Float16)(float)vv[4 + j];
    }
    *(f16x4*)&vs[slv][co] = a;
    *(f16x4*)&vs[slv][co + 4] = b;
  }
  __syncthreads();

  {
    int sl = t >> 2, role = t & 3;
    int isK = role >> 1, half = role & 1;
    const __bf16* src = qkv + (size_t)(s0 + sl) * (NHEAD * 3 * HDIM) + h * 384 +
                        isK * 128 + half * 64;
    float scale = isK ? 1.f : 0.08838834764831845f;  // 1/sqrt(128)
    float x[64];
    bf16x8 buf[8];
#pragma unroll
    for (int c = 0; c < 8; c++) buf[c] = *(const bf16x8*)(src + c * 8);
#pragma unroll
    for (int c = 0; c < 8; c++)
#pragma unroll
      for (int j = 0; j < 8; j++) x[c * 8 + j] = (float)buf[c][j];
    bf16x8 ob[8];
#pragma unroll
    for (int i = 0; i < 64; i++) {
      int ii = i & 31;
      float cv = cs[sl][half][0][ii], sv = cs[sl][half][1][ii];
      float partner = (i < 32) ? x[i + 32] : x[i - 32];
      float sgn = (i < 32) ? -1.f : 1.f;
      float o = (x[i] * cv + sgn * partner * sv) * scale;
      ob[i >> 3][i & 7] = (__bf16)o;
    }
    __bf16* dst = (isK ? K : Q) + ((size_t)h * S_LEN + s0 + sl) * HDIM + half * 64;
#pragma unroll
    for (int c = 0; c < 8; c++) *(bf16x8*)(dst + c * 8) = ob[c];
  }

#pragma unroll
  for (int c = 0; c < 4; c++) {
    int chunk = c * 256 + t;
    int d = chunk >> 3, so = (chunk & 7) * 8;
    f16x8 o;
#pragma unroll
    for (int j = 0; j < 8; j++) o[j] = vs[so + j][d];
    *(f16x8*)(VT + ((size_t)h * HDIM + d) * S_LEN + s0 + so) = o;
  }
}

// ---------------------------- Flash attention ------------------------------
// grid = 512; balanced pairing: blocks b and b+256 land on the same CU under
// round-robin dispatch, so qb(b) + qb(b+256) == 15 (equal per-CU work).
// 4 waves/block, wave owns 32 q rows. KVBLK=32, V prefetched before softmax.
__global__ __launch_bounds__(256, 2) void attn_kernel(
    const __bf16* __restrict__ Q, const __bf16* __restrict__ K,
    const _Float16* __restrict__ VT, __bf16* __restrict__ ctx) {
  int b = blockIdx.x;
  int h = b & 31;
  int x = b >> 5;                          // 0..15
  int qb = (b < 256) ? (15 - x) : (x - 8); // pairs (15-x, x') sum to 15
  int w = threadIdx.x >> 6, l = threadIdx.x & 63;
  int lr = l & 15, lg = l >> 4;
  int q0 = qb * 128 + w * 32;
  const __bf16* Qh = Q + (size_t)h * S_LEN * HDIM;
  const __bf16* Kh = K + (size_t)h * S_LEN * HDIM;
  const _Float16* Vh = VT + (size_t)h * HDIM * S_LEN;

  bf16x8 qfA[4], qfB[4];
#pragma unroll
  for (int kk = 0; kk < 4; kk++) {
    qfA[kk] = *(const bf16x8*)(Qh + (size_t)(q0 + lr) * HDIM + kk * 32 + lg * 8);
    qfB[kk] =
        *(const bf16x8*)(Qh + (size_t)(q0 + 16 + lr) * HDIM + kk * 32 + lg * 8);
  }

  f32x4 accA[8], accB[8];
#pragma unroll
  for (int tt = 0; tt < 8; tt++) { accA[tt] = 0.f; accB[tt] = 0.f; }
  float mA = -INFINITY, lsA = 0.f, mB = -INFINITY, lsB = 0.f;
  int qgA = q0 + lr, qgB = q0 + 16 + lr;
  int qmax = q0 + 31;

  for (int kv0 = 0; kv0 <= qmax; kv0 += 32) {
    f32x4 stA0 = 0.f, stA1 = 0.f, stB0 = 0.f, stB1 = 0.f;
#pragma unroll
    for (int kk = 0; kk < 4; kk++) {
      bf16x8 kf0 =
          *(const bf16x8*)(Kh + (size_t)(kv0 + lr) * HDIM + kk * 32 + lg * 8);
      bf16x8 kf1 = *(const bf16x8*)(Kh + (size_t)(kv0 + 16 + lr) * HDIM +
                                    kk * 32 + lg * 8);
      stA0 = __builtin_amdgcn_mfma_f32_16x16x32_bf16(kf0, qfA[kk], stA0, 0, 0, 0);
      stB0 = __builtin_amdgcn_mfma_f32_16x16x32_bf16(kf0, qfB[kk], stB0, 0, 0, 0);
      stA1 = __builtin_amdgcn_mfma_f32_16x16x32_bf16(kf1, qfA[kk], stA1, 0, 0, 0);
      stB1 = __builtin_amdgcn_mfma_f32_16x16x32_bf16(kf1, qfB[kk], stB1, 0, 0, 0);
    }

    // ---- V prefetch (independent of softmax; hides L2 latency) ----
    f16x4 vb0[8], vb1[8];
#pragma unroll
    for (int tt = 0; tt < 8; tt++) {
      const _Float16* vcol = Vh + (size_t)(tt * 16 + lr) * S_LEN;
      vb0[tt] = *(const f16x4*)(vcol + kv0 + lg * 4);
      vb1[tt] = *(const f16x4*)(vcol + kv0 + 16 + lg * 4);
    }

    float tmA = -INFINITY, tmB = -INFINITY;
#pragma unroll
    for (int j = 0; j < 4; j++) {
      int kvg0 = kv0 + lg * 4 + j;
      int kvg1 = kvg0 + 16;
      if (kvg0 > qgA) stA0[j] = -INFINITY;
      if (kvg1 > qgA) stA1[j] = -INFINITY;
      if (kvg0 > qgB) stB0[j] = -INFINITY;
      if (kvg1 > qgB) stB1[j] = -INFINITY;
      tmA = fmaxf(tmA, fmaxf(stA0[j], stA1[j]));
      tmB = fmaxf(tmB, fmaxf(stB0[j], stB1[j]));
    }
    tmA = fmaxf(tmA, __shfl_xor(tmA, 16));
    tmA = fmaxf(tmA, __shfl_xor(tmA, 32));
    tmB = fmaxf(tmB, __shfl_xor(tmB, 16));
    tmB = fmaxf(tmB, __shfl_xor(tmB, 32));
    int need = __any((tmA > mA) || (tmB > mB));
    float mnA = fmaxf(mA, tmA), mnB = fmaxf(mB, tmB);

    f16x4 paA0, paA1, paB0, paB1;
    float tsA = 0.f, tsB = 0.f;
#pragma unroll
    for (int j = 0; j < 4; j++) {
      float pA0 = __expf(stA0[j] - mnA);
      float pA1 = __expf(stA1[j] - mnA);
      float pB0 = __expf(stB0[j] - mnB);
      float pB1 = __expf(stB1[j] - mnB);
      tsA += pA0 + pA1;
      tsB += pB0 + pB1;
      paA0[j] = (_Float16)pA0; paA1[j] = (_Float16)pA1;
      paB0[j] = (_Float16)pB0; paB1[j] = (_Float16)pB1;
    }
    tsA += __shfl_xor(tsA, 16);
    tsA += __shfl_xor(tsA, 32);
    tsB += __shfl_xor(tsB, 16);
    tsB += __shfl_xor(tsB, 32);

    if (need) {
      float scA = __expf(mA - mnA), scB = __expf(mB - mnB);
      lsA = lsA * scA + tsA;
      lsB = lsB * scB + tsB;
      float sAj[4], sBj[4];
#pragma unroll
      for (int j = 0; j < 4; j++) {
        sAj[j] = __shfl(scA, lg * 4 + j);
        sBj[j] = __shfl(scB, lg * 4 + j);
      }
#pragma unroll
      for (int tt = 0; tt < 8; tt++)
#pragma unroll
        for (int j = 0; j < 4; j++) {
          accA[tt][j] *= sAj[j];
          accB[tt][j] *= sBj[j];
        }
    } else {
      lsA += tsA;
      lsB += tsB;
    }
    mA = mnA; mB = mnB;

#pragma unroll
    for (int tt = 0; tt < 8; tt++) {
      accA[tt] =
          __builtin_amdgcn_mfma_f32_16x16x16f16(paA0, vb0[tt], accA[tt], 0, 0, 0);
      accB[tt] =
          __builtin_amdgcn_mfma_f32_16x16x16f16(paB0, vb0[tt], accB[tt], 0, 0, 0);
      accA[tt] =
          __builtin_amdgcn_mfma_f32_16x16x16f16(paA1, vb1[tt], accA[tt], 0, 0, 0);
      accB[tt] =
          __builtin_amdgcn_mfma_f32_16x16x16f16(paB1, vb1[tt], accB[tt], 0, 0, 0);
    }
  }

  float rA[4], rB[4];
#pragma unroll
  for (int j = 0; j < 4; j++) {
    rA[j] = 1.f / __shfl(lsA, lg * 4 + j);
    rB[j] = 1.f / __shfl(lsB, lg * 4 + j);
  }
#pragma unroll
  for (int tt = 0; tt < 8; tt++) {
#pragma unroll
    for (int j = 0; j < 4; j++) {
      int qoA = q0 + lg * 4 + j;
      int qoB = q0 + 16 + lg * 4 + j;
      ctx[(size_t)qoA * (NHEAD * HDIM) + h * HDIM + tt * 16 + lr] =
          (__bf16)(accA[tt][j] * rA[j]);
      ctx[(size_t)qoB * (NHEAD * HDIM) + h * HDIM + tt * 16 + lr] =
          (__bf16)(accB[tt][j] * rB[j]);
    }
  }
}

// ---------------------------------------------------------------------------
extern "C" void kernel_launch(void* const* d_in, const int* in_sizes, int n_in,
                              void* d_out, int out_size, void* d_ws,
                              size_t ws_size, hipStream_t stream) {
  const float* hs = (const float*)d_in[0];
  const int* pos_ids = (const int*)d_in[1];
  const float* Wqkv = (const float*)d_in[4];
  const float* bqkv = (const float*)d_in[5];
  const float* Wd = (const float*)d_in[6];
  const float* bd = (const float*)d_in[7];
  float* out = (float*)d_out;

  char* ws = (char*)d_ws;
  constexpr size_t OFF_W = 16777216ULL;
  constexpr size_t OFF_QKV = OFF_W + 100663296ULL;
  constexpr size_t OFF_Q = OFF_QKV + 50331648ULL;
  constexpr size_t OFF_K = OFF_Q + 16777216ULL;
  constexpr size_t OFF_V = OFF_K + 16777216ULL;
  __bf16* hsb = (__bf16*)(ws);
  __bf16* wqkvb = (__bf16*)(ws + OFF_W);
  __bf16* wdb = (__bf16*)(ws + OFF_W);  // aliases wqkvb (dead after GEMM1)
  // split-K partials live in the free tail of the wqkv region (after GEMM1):
  float* pk = (float*)(ws + OFF_W + 33554432ULL);  // 2 x 32MB
  __bf16* qkvb = (__bf16*)(ws + OFF_QKV);
  __bf16* ctxb = qkvb;                  // aliases qkv (dead after rope)
  __bf16* Qb = (__bf16*)(ws + OFF_Q);
  __bf16* Kb = (__bf16*)(ws + OFF_K);
  _Float16* Vtb = (_Float16*)(ws + OFF_V);

  // Merged convert: hs (2M chunks) + Wqkv (12.6M chunks) in one launch.
  const int n4_hs = S_LEN * HID / 4;
  const int n4_w = 3 * HID * HID / 4;
  cvt2_kernel<<<(n4_hs + n4_w + 255) / 256, 256, 0, stream>>>(
      hs, hsb, n4_hs, Wqkv, wqkvb, n4_w);

  // GEMM1: [2048,4096] x [12288,4096]^T -> bf16 qkv. 8x48 tiles of 256^2.
  gemm256_kernel<1><<<8 * 48, 512, 0, stream>>>(hsb, wqkvb, bqkv, qkvb, S_LEN,
                                                3 * HID, HID, HID, 8, 1);

  cvt_f32_bf16_kernel<<<(HID * HID) / 4 / 256, 256, 0, stream>>>(
      Wd, wdb, HID * HID / 4);

  rope_kernel<<<NHEAD * (S_LEN / 64), 256, 0, stream>>>(qkvb, pos_ids, Qb, Kb,
                                                        Vtb);

  attn_kernel<<<NHEAD * (S_LEN / 128), 256, 0, stream>>>(Qb, Kb, Vtb, ctxb);

  // GEMM2 split-K=2: 256 blocks (1/CU), f32 partials, then reduce + bias.
  gemm256_kernel<2><<<2 * 8 * 16, 512, 0, stream>>>(ctxb, wdb, bd, pk, S_LEN,
                                                    HID, HID, HID / 2, 8, 2);
  reduce_addbias_kernel<<<(S_LEN * HID) / 4 / 256, 256, 0, stream>>>(
      pk, pk + (size_t)S_LEN * HID, bd, out);
}